// Round 2
// baseline (318.655 us; speedup 1.0000x reference)
//
#include <hip/hip_runtime.h>

// out[b,s,d] = alpha * sum_{j=1..P} beta^{j-1} x[b,s-j,d] + pf[d] + pb[((s>>5)-d)&31]
// Sliding window: y(t+1) = beta*y(t) + alpha*x[t] - alpha*beta^P*x[t-P]
// No LDS, no barriers: stream from global (L2/L3 absorb reuse), 4 independent
// chains per thread (float4 over d) for ILP, CHAIN=32 outputs per chain.

constexpr int S     = 1024;
constexpr int D     = 32;
constexpr int CHAIN = 32;            // s-extent per thread (32-aligned => s>>5 const)
constexpr int NTHR  = (S / CHAIN) * (D / 4);   // 32 chunks * 8 dgroups = 256

__global__ __launch_bounds__(NTHR)
void attn_pred_kernel(const float* __restrict__ x,
                      const float* __restrict__ alpha_p,
                      const float* __restrict__ beta_p,
                      const float* __restrict__ pos_fwd,
                      const float* __restrict__ pos_bwd,
                      const int*   __restrict__ past_p,
                      float* __restrict__ out)
{
    const int tid   = threadIdx.x;
    const int b     = blockIdx.x;
    const int dg    = tid & 7;            // float4 group over d: d0 = dg*4
    const int chunk = tid >> 3;           // 0..31, sstart = chunk*32
    const int sstart = chunk * CHAIN;

    const float alpha = alpha_p[0];
    const float beta  = beta_p[0];
    const int   P     = past_p[0];        // 128

    double bp = 1.0;
    for (int i = 0; i < P; ++i) bp *= (double)beta;
    const float abP = alpha * (float)bp;

    const float4* xg = reinterpret_cast<const float4*>(x) + (size_t)b * S * (D / 4);

    // ---- prime: y(sstart) = alpha * Horner over x[sstart-P .. sstart-1] ----
    float4 y = make_float4(0.f, 0.f, 0.f, 0.f);
    const int sbase = sstart - P;
    #pragma unroll 8
    for (int j = 0; j < P; ++j) {
        const int s = sbase + j;
        float4 v = make_float4(0.f, 0.f, 0.f, 0.f);
        if (s >= 0) v = xg[s * (D / 4) + dg];
        y.x = fmaf(y.x, beta, v.x);
        y.y = fmaf(y.y, beta, v.y);
        y.z = fmaf(y.z, beta, v.z);
        y.w = fmaf(y.w, beta, v.w);
    }
    y.x *= alpha; y.y *= alpha; y.z *= alpha; y.w *= alpha;

    // ---- positional bias (constant across this thread's 32-aligned chain) ----
    const int d0 = dg * 4;
    const float4 pf = reinterpret_cast<const float4*>(pos_fwd)[dg];
    float4 add;
    add.x = pf.x + pos_bwd[(chunk - (d0 + 0)) & (D - 1)];
    add.y = pf.y + pos_bwd[(chunk - (d0 + 1)) & (D - 1)];
    add.z = pf.z + pos_bwd[(chunk - (d0 + 2)) & (D - 1)];
    add.w = pf.w + pos_bwd[(chunk - (d0 + 3)) & (D - 1)];

    // ---- chain: write y(s)+bias, advance window ----
    float4* og = reinterpret_cast<float4*>(out) + ((size_t)b * S + sstart) * (D / 4) + dg;
    #pragma unroll 8
    for (int i = 0; i < CHAIN; ++i) {
        float4 o;
        o.x = y.x + add.x; o.y = y.y + add.y; o.z = y.z + add.z; o.w = y.w + add.w;
        og[i * (D / 4)] = o;

        const int s  = sstart + i;
        const int sl = s - P;
        const float4 xt = xg[s * (D / 4) + dg];
        float4 xl = make_float4(0.f, 0.f, 0.f, 0.f);
        if (sl >= 0) xl = xg[sl * (D / 4) + dg];

        y.x = fmaf(beta, y.x, fmaf(alpha, xt.x, -abP * xl.x));
        y.y = fmaf(beta, y.y, fmaf(alpha, xt.y, -abP * xl.y));
        y.z = fmaf(beta, y.z, fmaf(alpha, xt.z, -abP * xl.z));
        y.w = fmaf(beta, y.w, fmaf(alpha, xt.w, -abP * xl.w));
    }
}

extern "C" void kernel_launch(void* const* d_in, const int* in_sizes, int n_in,
                              void* d_out, int out_size, void* d_ws, size_t ws_size,
                              hipStream_t stream) {
    const float* x  = (const float*)d_in[0];
    const float* al = (const float*)d_in[1];
    const float* be = (const float*)d_in[2];
    const float* pf = (const float*)d_in[3];
    const float* pb = (const float*)d_in[4];
    const int*   ps = (const int*)d_in[5];
    float* out = (float*)d_out;

    const int B = in_sizes[0] / (S * D);      // 1024
    attn_pred_kernel<<<dim3(B), NTHR, 0, stream>>>(x, al, be, pf, pb, ps, out);
}

// Round 3
// 259.163 us; speedup vs baseline: 1.2296x; 1.2296x over previous
//
#include <hip/hip_runtime.h>

// out[b,s,d] = alpha*sum_{j=1..P} beta^{j-1} x[b,s-j,d] + pf[d] + pb[((s>>5)-d)&31]
// Key identity: windowed FIR == pure IIR on z[t] = alpha*x[t] - alpha*beta^P*x[t-P]:
//   y(t+1) = beta*y(t) + z[t],  y(0) = 0   (telescopes exactly, no priming)
// One block = one row b. 256 thr = 8 float4-dgroups x 32 chunks of 32.
// Pass A: chunk-local decayed sums; tiny LDS exclusive scan of carries (beta^32);
// Pass B: re-read (L1/L2-warm), emit with nontemporal stores (protect L3 from
// write-stream thrash -- R2's FETCH blowup).

typedef float f32x4 __attribute__((ext_vector_type(4)));

constexpr int S    = 1024;
constexpr int D    = 32;
constexpr int CL   = 32;    // chunk length (32-aligned => s>>5 const per chunk)
constexpr int NCH  = S / CL;            // 32 chunks
constexpr int NTHR = NCH * (D / 4);     // 256

__global__ __launch_bounds__(NTHR, 4)
void attn_pred_kernel(const float* __restrict__ x,
                      const float* __restrict__ alpha_p,
                      const float* __restrict__ beta_p,
                      const float* __restrict__ pos_fwd,
                      const float* __restrict__ pos_bwd,
                      const int*   __restrict__ past_p,
                      float* __restrict__ out)
{
    __shared__ f32x4 lcar[NCH][D / 4];   // 4 KiB

    const int tid = threadIdx.x;
    const int b   = blockIdx.x;
    const int dg  = tid & 7;             // float4 group over d
    const int c   = tid >> 3;            // chunk 0..31
    const int s0  = c * CL;

    const float alpha = alpha_p[0];
    const float beta  = beta_p[0];
    const int   P     = past_p[0];       // 128

    double bp = 1.0;
    for (int i = 0; i < P; ++i) bp *= (double)beta;
    const float abP = alpha * (float)bp;
    double bcl = 1.0;
    for (int i = 0; i < CL; ++i) bcl *= (double)beta;
    const float bCL = (float)bcl;        // beta^32

    const f32x4* xg = reinterpret_cast<const f32x4*>(x) + (size_t)b * S * (D / 4);

    // ---- pass A: l = sum_{i<CL} beta^{CL-1-i} z[s0+i] ----
    f32x4 l = {0.f, 0.f, 0.f, 0.f};
    #pragma unroll 8
    for (int i = 0; i < CL; ++i) {
        const int s  = s0 + i;
        const int sl = s - P;
        const f32x4 xt = xg[s * (D / 4) + dg];
        f32x4 xl = {0.f, 0.f, 0.f, 0.f};
        if (sl >= 0) xl = xg[sl * (D / 4) + dg];
        l.x = fmaf(beta, l.x, fmaf(alpha, xt.x, -abP * xl.x));
        l.y = fmaf(beta, l.y, fmaf(alpha, xt.y, -abP * xl.y));
        l.z = fmaf(beta, l.z, fmaf(alpha, xt.z, -abP * xl.z));
        l.w = fmaf(beta, l.w, fmaf(alpha, xt.w, -abP * xl.w));
    }
    lcar[c][dg] = l;
    __syncthreads();

    // ---- exclusive scan of chunk carries: y(s0) per (chunk, dg) ----
    if (tid < D / 4) {
        f32x4 run = {0.f, 0.f, 0.f, 0.f};
        for (int cc = 0; cc < NCH; ++cc) {
            const f32x4 v = lcar[cc][tid];
            lcar[cc][tid] = run;
            run.x = fmaf(bCL, run.x, v.x);
            run.y = fmaf(bCL, run.y, v.y);
            run.z = fmaf(bCL, run.z, v.z);
            run.w = fmaf(bCL, run.w, v.w);
        }
    }
    __syncthreads();
    f32x4 y = lcar[c][dg];

    // ---- positional bias (constant across the 32-aligned chunk) ----
    const int d0 = dg * 4;
    const f32x4 pf = reinterpret_cast<const f32x4*>(pos_fwd)[dg];
    f32x4 add;
    add.x = pf.x + pos_bwd[(c - (d0 + 0)) & (D - 1)];
    add.y = pf.y + pos_bwd[(c - (d0 + 1)) & (D - 1)];
    add.z = pf.z + pos_bwd[(c - (d0 + 2)) & (D - 1)];
    add.w = pf.w + pos_bwd[(c - (d0 + 3)) & (D - 1)];

    // ---- pass B: re-run recurrence, emit outputs (nontemporal) ----
    f32x4* og = reinterpret_cast<f32x4*>(out) + ((size_t)b * S + s0) * (D / 4) + dg;
    #pragma unroll 8
    for (int i = 0; i < CL; ++i) {
        f32x4 o;
        o.x = y.x + add.x; o.y = y.y + add.y;
        o.z = y.z + add.z; o.w = y.w + add.w;
        __builtin_nontemporal_store(o, &og[i * (D / 4)]);

        const int s  = s0 + i;
        const int sl = s - P;
        const f32x4 xt = xg[s * (D / 4) + dg];
        f32x4 xl = {0.f, 0.f, 0.f, 0.f};
        if (sl >= 0) xl = xg[sl * (D / 4) + dg];
        y.x = fmaf(beta, y.x, fmaf(alpha, xt.x, -abP * xl.x));
        y.y = fmaf(beta, y.y, fmaf(alpha, xt.y, -abP * xl.y));
        y.z = fmaf(beta, y.z, fmaf(alpha, xt.z, -abP * xl.z));
        y.w = fmaf(beta, y.w, fmaf(alpha, xt.w, -abP * xl.w));
    }
}

extern "C" void kernel_launch(void* const* d_in, const int* in_sizes, int n_in,
                              void* d_out, int out_size, void* d_ws, size_t ws_size,
                              hipStream_t stream) {
    const float* x  = (const float*)d_in[0];
    const float* al = (const float*)d_in[1];
    const float* be = (const float*)d_in[2];
    const float* pf = (const float*)d_in[3];
    const float* pb = (const float*)d_in[4];
    const int*   ps = (const int*)d_in[5];
    float* out = (float*)d_out;

    const int B = in_sizes[0] / (S * D);      // 1024
    attn_pred_kernel<<<dim3(B), NTHR, 0, stream>>>(x, al, be, pf, pb, ps, out);
}

// Round 4
// 254.656 us; speedup vs baseline: 1.2513x; 1.0177x over previous
//
#include <hip/hip_runtime.h>

// out[b,s,d] = alpha*sum_{j=1..P} beta^{j-1} x[b,s-j,d] + pf[d] + pb[((s>>5)-d)&31]
// Full-row blocks: 512 threads = 64 chunks(CL=16) x 8 float4-dgroups -> 8 waves/block,
// 1024 blocks x 8 = 8192 waves = 100% of chip wave slots (R3 was grid-capped at 50%).
// Pass A: PURE decayed chunk sums A_c (16 loads; the P=128 lag = exactly 8 chunks, so
// the scan forms z-chunk sums L_c = alpha*(A_c - beta^P * A_{c-8}) without re-reading).
// Scan: 8 threads, 64 steps, exclusive carries (beta^16 chaining) -> exact y at chunk
// starts (row carry-in is exactly 0). Pass B: emit 16 outputs/thread, NT stores.

typedef float f32x4 __attribute__((ext_vector_type(4)));

constexpr int S    = 1024;
constexpr int D    = 32;
constexpr int CL   = 16;              // 16-runs stay inside one 32-block => s>>5 const
constexpr int NCH  = S / CL;          // 64 chunks
constexpr int LAG  = 8;               // P / CL
constexpr int NTHR = NCH * (D / 4);   // 512

__global__ __launch_bounds__(NTHR, 8)
void attn_pred_kernel(const float* __restrict__ x,
                      const float* __restrict__ alpha_p,
                      const float* __restrict__ beta_p,
                      const float* __restrict__ pos_fwd,
                      const float* __restrict__ pos_bwd,
                      const int*   __restrict__ past_p,
                      float* __restrict__ out)
{
    __shared__ f32x4 sA[NCH][D / 4];  // 4 KiB: pure chunk sums
    __shared__ f32x4 sC[NCH][D / 4];  // 4 KiB: exclusive carries

    const int tid = threadIdx.x;
    const int b   = blockIdx.x;
    const int dg  = tid & 7;          // float4 group over d
    const int c   = tid >> 3;         // chunk 0..63
    const int s0  = c * CL;

    const float alpha = alpha_p[0];
    const float beta  = beta_p[0];
    const int   P     = past_p[0];    // 128

    // beta^P by squaring (double), beta^CL by 4 squarings
    double bb = (double)beta, bpd = 1.0;
    for (int e = P; e; e >>= 1) { if (e & 1) bpd *= bb; bb *= bb; }
    const float bP = (float)bpd;
    double b16 = (double)beta;
    for (int i = 0; i < 4; ++i) b16 *= b16;
    const float bCL = (float)b16;     // beta^16

    const f32x4* xg = reinterpret_cast<const f32x4*>(x) + (size_t)b * S * (D / 4) + dg;

    // ---- pass A: A_c = sum_{i<CL} beta^{CL-1-i} x[s0+i]  (pure, 16 loads) ----
    f32x4 A = {0.f, 0.f, 0.f, 0.f};
    #pragma unroll 8
    for (int i = 0; i < CL; ++i) {
        const f32x4 v = xg[(s0 + i) * (D / 4)];
        A.x = fmaf(beta, A.x, v.x);
        A.y = fmaf(beta, A.y, v.y);
        A.z = fmaf(beta, A.z, v.z);
        A.w = fmaf(beta, A.w, v.w);
    }
    sA[c][dg] = A;
    __syncthreads();

    // ---- scan (8 threads, one per dg): exclusive carries over 64 chunks ----
    if (tid < D / 4) {
        f32x4 run = {0.f, 0.f, 0.f, 0.f};
        for (int cc = 0; cc < NCH; ++cc) {
            sC[cc][tid] = run;
            const f32x4 Ac = sA[cc][tid];
            f32x4 z;
            if (cc >= LAG) {
                const f32x4 Al = sA[cc - LAG][tid];
                z.x = alpha * fmaf(-bP, Al.x, Ac.x);
                z.y = alpha * fmaf(-bP, Al.y, Ac.y);
                z.z = alpha * fmaf(-bP, Al.z, Ac.z);
                z.w = alpha * fmaf(-bP, Al.w, Ac.w);
            } else {
                z.x = alpha * Ac.x; z.y = alpha * Ac.y;
                z.z = alpha * Ac.z; z.w = alpha * Ac.w;
            }
            run.x = fmaf(bCL, run.x, z.x);
            run.y = fmaf(bCL, run.y, z.y);
            run.z = fmaf(bCL, run.z, z.z);
            run.w = fmaf(bCL, run.w, z.w);
        }
    }
    __syncthreads();
    f32x4 y = sC[c][dg];

    // ---- positional bias (s>>5 == c>>1, constant over the chunk) ----
    const int d0 = dg * 4;
    const int q  = c >> 1;
    const f32x4 pf = reinterpret_cast<const f32x4*>(pos_fwd)[dg];
    f32x4 add;
    add.x = pf.x + pos_bwd[(q - (d0 + 0)) & (D - 1)];
    add.y = pf.y + pos_bwd[(q - (d0 + 1)) & (D - 1)];
    add.z = pf.z + pos_bwd[(q - (d0 + 2)) & (D - 1)];
    add.w = pf.w + pos_bwd[(q - (d0 + 3)) & (D - 1)];

    // ---- pass B: emit 16 outputs, advance windowed recurrence ----
    const float aP = alpha * bP;           // alpha*beta^P
    const bool haveL = (c >= LAG);         // wave-uniform
    f32x4* og = reinterpret_cast<f32x4*>(out) + ((size_t)b * S + s0) * (D / 4) + dg;
    #pragma unroll 4
    for (int i = 0; i < CL; ++i) {
        f32x4 o;
        o.x = y.x + add.x; o.y = y.y + add.y;
        o.z = y.z + add.z; o.w = y.w + add.w;
        __builtin_nontemporal_store(o, &og[i * (D / 4)]);

        const f32x4 xt = xg[(s0 + i) * (D / 4)];
        f32x4 xl = {0.f, 0.f, 0.f, 0.f};
        if (haveL) xl = xg[(s0 - P + i) * (D / 4)];
        y.x = fmaf(beta, y.x, fmaf(alpha, xt.x, -aP * xl.x));
        y.y = fmaf(beta, y.y, fmaf(alpha, xt.y, -aP * xl.y));
        y.z = fmaf(beta, y.z, fmaf(alpha, xt.z, -aP * xl.z));
        y.w = fmaf(beta, y.w, fmaf(alpha, xt.w, -aP * xl.w));
    }
}

extern "C" void kernel_launch(void* const* d_in, const int* in_sizes, int n_in,
                              void* d_out, int out_size, void* d_ws, size_t ws_size,
                              hipStream_t stream) {
    const float* x  = (const float*)d_in[0];
    const float* al = (const float*)d_in[1];
    const float* be = (const float*)d_in[2];
    const float* pf = (const float*)d_in[3];
    const float* pb = (const float*)d_in[4];
    const int*   ps = (const int*)d_in[5];
    float* out = (float*)d_out;

    const int B = in_sizes[0] / (S * D);   // 1024
    attn_pred_kernel<<<dim3(B), NTHR, 0, stream>>>(x, al, be, pf, pb, ps, out);
}